// Round 7
// baseline (692.490 us; speedup 1.0000x reference)
//
#include <hip/hip_runtime.h>
#include <hip/hip_bf16.h>
#include <stdint.h>

#define B_ 128
#define T_ 255
#define N_ 256
#define H_ 256

typedef _Float16 f16;
typedef _Float16 f16x2 __attribute__((ext_vector_type(2)));
typedef _Float16 f16x8 __attribute__((ext_vector_type(8)));
typedef float f32x4 __attribute__((ext_vector_type(4)));

// ---------------- K0: pack W_lstm (transposed) and U_lstm (MFMA-A-fragment
// order) to f16.
// u_mfma fragment layout (matches the verified k3 operand mapping):
//   frag (w, f=j*8+q), lane L, element e (f16):
//     A[m][k] with m = z-col = 128w+16j+(L&15), k = 32q+(L>>4)*8+e
//     = U[32q+(L>>4)*8+e][128w+16j+(L&15)]
__global__ __launch_bounds__(256) void k0_pack(const float* __restrict__ Wl,
                                               const float* __restrict__ Ul,
                                               uint32_t* __restrict__ um,
                                               f16* __restrict__ wt) {
  int idx = blockIdx.x * 256 + threadIdx.x;
  if (idx < 256 * 1024) {              // wt[n][k] = Wl[k][n]
    int n = idx >> 8, k = idx & 255;
    wt[n * 256 + k] = (f16)Wl[k * 1024 + n];
  }
  if (idx < 131072) {                  // u_mfma dword idx
    int d = idx;
    int w = d >> 14, f = (d >> 8) & 63, L = (d >> 2) & 63, ep = d & 3;
    int j = f >> 3, q = f & 7;
    int r0 = 32 * q + ((L >> 4) << 3) + 2 * ep;
    int c = 128 * w + 16 * j + (L & 15);
    f16x2 v;
    v.x = (f16)Ul[r0 * 1024 + c];
    v.y = (f16)Ul[(r0 + 1) * 1024 + c];
    um[d] = __builtin_bit_cast(uint32_t, v);
  }
}

// ---------------- K1: alpha[b][n] = softmax_n( sum_t X[b,t,n] * Wa[512+t] )
__global__ __launch_bounds__(256) void k1_alpha(const float* __restrict__ X,
                                                const float* __restrict__ Wa,
                                                float* __restrict__ alpha) {
  int b = blockIdx.x, n = threadIdx.x;
  const float* xb = X + b * (T_ * N_) + n;
  float a0 = 0.f, a1 = 0.f, a2 = 0.f, a3 = 0.f;
  int t = 0;
  for (; t + 4 <= T_; t += 4) {
    a0 += xb[(t + 0) * N_] * Wa[512 + t + 0];
    a1 += xb[(t + 1) * N_] * Wa[512 + t + 1];
    a2 += xb[(t + 2) * N_] * Wa[512 + t + 2];
    a3 += xb[(t + 3) * N_] * Wa[512 + t + 3];
  }
  for (; t < T_; ++t) a0 += xb[t * N_] * Wa[512 + t];
  float e = (a0 + a1) + (a2 + a3);

  __shared__ float red[4];
  float m = e;
  for (int off = 32; off > 0; off >>= 1) m = fmaxf(m, __shfl_xor(m, off));
  int wid = n >> 6;
  if ((n & 63) == 0) red[wid] = m;
  __syncthreads();
  m = fmaxf(fmaxf(red[0], red[1]), fmaxf(red[2], red[3]));
  float ex = __expf(e - m);
  float s = ex;
  for (int off = 32; off > 0; off >>= 1) s += __shfl_xor(s, off);
  __syncthreads();
  if ((n & 63) == 0) red[wid] = s;
  __syncthreads();
  s = (red[0] + red[1]) + (red[2] + red[3]);
  alpha[b * N_ + n] = ex / s;
}

// ---------------- K2: X_tilde = alpha (broadcast over t) * X   (exact fp32)
__global__ __launch_bounds__(256) void k2_xtilde(const float4* __restrict__ X4,
                                                 const float* __restrict__ alpha,
                                                 float4* __restrict__ out4) {
  int i = blockIdx.x * 256 + threadIdx.x;  // over B*T*64 float4s
  if (i < B_ * T_ * 64) {
    int n4 = i & 63;
    int bt = i >> 6;
    int b = bt / T_;
    const float4* A4 = (const float4*)alpha;
    float4 x = X4[i], al = A4[b * 64 + n4];
    float4 r;
    r.x = x.x * al.x; r.y = x.y * al.y; r.z = x.z * al.z; r.w = x.w * al.w;
    out4[i] = r;
  }
}

// ---------------- K3: XW = X_tilde @ W_lstm + b_lstm  -> f16 (32640 x 1024)
#define LDA 40  // f16 row stride in LDS (16B-aligned rows, bank-spread)
__global__ __launch_bounds__(256, 2) void k3_gemm(const float* __restrict__ A,
                                                  const f16* __restrict__ Bt,
                                                  const float* __restrict__ bias,
                                                  f16* __restrict__ Cw) {
  __shared__ f16 As[128 * LDA];
  __shared__ f16 Bs[128 * LDA];
  int tid = threadIdx.x;
  int mt = blockIdx.x;  // 0..254
  int nt = blockIdx.y;  // 0..7
  int lane = tid & 63, wid = tid >> 6;
  int wm = (wid >> 1) * 64, wn = (wid & 1) * 64;
  f32x4 acc[4][4] = {};

  for (int k0 = 0; k0 < 256; k0 += 32) {
    __syncthreads();
#pragma unroll
    for (int it = 0; it < 4; ++it) {  // A: 128 rows x 32 f32 -> f16
      int idx = tid + it * 256;
      int r = idx >> 3, q = idx & 7;
      float4 v = *(const float4*)(A + (mt * 128 + r) * 256 + k0 + q * 4);
      f16x2 p0, p1;
      p0.x = (f16)v.x; p0.y = (f16)v.y; p1.x = (f16)v.z; p1.y = (f16)v.w;
      uint2 w;
      w.x = __builtin_bit_cast(uint32_t, p0);
      w.y = __builtin_bit_cast(uint32_t, p1);
      *(uint2*)(&As[r * LDA + q * 4]) = w;
    }
#pragma unroll
    for (int it = 0; it < 2; ++it) {  // B (already transposed): 128 rows x 32 f16
      int idx = tid + it * 256;
      int r = idx >> 2, q = idx & 3;
      uint4 v = *(const uint4*)(Bt + (nt * 128 + r) * 256 + k0 + q * 8);
      *(uint4*)(&Bs[r * LDA + q * 8]) = v;
    }
    __syncthreads();
    int kb = (lane >> 4) * 8;
    f16x8 af[4], bf[4];
#pragma unroll
    for (int i = 0; i < 4; ++i)
      af[i] = *(const f16x8*)(&As[(wm + i * 16 + (lane & 15)) * LDA + kb]);
#pragma unroll
    for (int j = 0; j < 4; ++j)
      bf[j] = *(const f16x8*)(&Bs[(wn + j * 16 + (lane & 15)) * LDA + kb]);
#pragma unroll
    for (int i = 0; i < 4; ++i)
#pragma unroll
      for (int j = 0; j < 4; ++j)
        acc[i][j] = __builtin_amdgcn_mfma_f32_16x16x32_f16(af[i], bf[j], acc[i][j], 0, 0, 0);
  }
  int colL = wn + (lane & 15);
  int rowB = wm + (lane >> 4) * 4;
#pragma unroll
  for (int j = 0; j < 4; ++j) {
    int ng = nt * 128 + colL + j * 16;
    float bv = bias[ng];
#pragma unroll
    for (int i = 0; i < 4; ++i)
#pragma unroll
      for (int r = 0; r < 4; ++r) {
        int mg = mt * 128 + rowB + i * 16 + r;
        Cw[mg * 1024 + ng] = (f16)(acc[i][j][r] + bv);
      }
  }
}

// ---------------- K4: sequential LSTM recurrence on the MFMA pipe.
// One block per batch, 512 thr / 8 waves; wave w owns z cols [128w,128w+128).
// z = h(1x256) @ U(256x1024) via mfma_f32_16x16x32_f16:
//   A = U^T fragments (m = z-col), B = h broadcast (n-independent).
// Per wave 64 MFMA/step: frags f=8j+q<46 asm-pinned in 46 uint4 quads
// (184 regs -> AGPR half of the unified file, consumed NATIVELY by MFMA —
// unlike r5/r6's v_dot2 which cannot read AGPRs), f>=46 from LDS (144 KB).
// No readlane, no h-broadcast storm (8 b128 h reads/thread/step).
#define UL4(F) uint4 a##F; \
  asm volatile("global_load_dwordx4 %0, %1, off" : "=v"(a##F) \
               : "v"(um4 + ((w * 64 + (F)) * 64 + L)));

#define MR(J, F, Q) acc##J = __builtin_amdgcn_mfma_f32_16x16x32_f16( \
    __builtin_bit_cast(f16x8, a##F), b##Q, acc##J, 0, 0, 0);
#define ML(J, FL, Q) acc##J = __builtin_amdgcn_mfma_f32_16x16x32_f16( \
    *(const f16x8*)(u_lds4 + (wl18 + (FL)) * 64 + L), b##Q, acc##J, 0, 0, 0);

#define BQ(Q) f16x8 b##Q = *(const f16x8*)&h_lds[32 * (Q) + hoff];
#define XLD(J) uint2 l##J = *(const uint2*)(xt + 16 * (J));
#define AINIT(J) f32x4 acc##J; { \
  f16x2 lo = __builtin_bit_cast(f16x2, l##J.x); \
  f16x2 hi = __builtin_bit_cast(f16x2, l##J.y); \
  acc##J[0] = (float)lo.x; acc##J[1] = (float)lo.y; \
  acc##J[2] = (float)hi.x; acc##J[3] = (float)hi.y; }
#define ZST(J) *(f32x4*)&z_lds[colbase + 16 * (J)] = acc##J;

__global__ __launch_bounds__(512)
void k4_recur(const float* __restrict__ X,
              const uint4* __restrict__ um4,
              const f16* __restrict__ xwf,
              float* __restrict__ Xenc) {
  __shared__ __align__(16) uint4 u_lds4[8 * 18 * 64];  // 147456 B: frags 46..63
  __shared__ __align__(16) f16 h_lds[256];             // 512 B
  __shared__ __align__(16) float z_lds[1024];          // 4096 B
  int tid = threadIdx.x, b = blockIdx.x;
  int w = tid >> 6, L = tid & 63;
  int wl18 = w * 18;
  int hoff = (L >> 4) << 3;                 // f16 units
  int colbase = 128 * w + ((L >> 4) << 2);  // z-col base for acc reg block

  UL4(0)  UL4(1)  UL4(2)  UL4(3)  UL4(4)  UL4(5)  UL4(6)  UL4(7)
  UL4(8)  UL4(9)  UL4(10) UL4(11) UL4(12) UL4(13) UL4(14) UL4(15)
  UL4(16) UL4(17) UL4(18) UL4(19) UL4(20) UL4(21) UL4(22) UL4(23)
  UL4(24) UL4(25) UL4(26) UL4(27) UL4(28) UL4(29) UL4(30) UL4(31)
  UL4(32) UL4(33) UL4(34) UL4(35) UL4(36) UL4(37) UL4(38) UL4(39)
  UL4(40) UL4(41) UL4(42) UL4(43) UL4(44) UL4(45)

#pragma unroll
  for (int f = 46; f < 64; ++f)
    u_lds4[(wl18 + f - 46) * 64 + L] = um4[(w * 64 + f) * 64 + L];

  float x00 = X[b * (T_ * N_)];
  float c_st = x00;
  if (tid < 256) h_lds[tid] = (f16)x00;
  asm volatile("s_waitcnt vmcnt(0)" ::: "memory");
  __syncthreads();

  const f16* xwb = xwf + (size_t)b * T_ * 1024;
  float* encb = Xenc + (size_t)b * T_ * N_;

  for (int t = 0; t < T_; ++t) {
    const f16* xt = xwb + t * 1024 + colbase;
    XLD(0) XLD(1) XLD(2) XLD(3) XLD(4) XLD(5) XLD(6) XLD(7)
    AINIT(0) AINIT(1) AINIT(2) AINIT(3) AINIT(4) AINIT(5) AINIT(6) AINIT(7)

    BQ(0)
    BQ(1)
    MR(0,0,0)  MR(1,8,0)  MR(2,16,0) MR(3,24,0) MR(4,32,0) MR(5,40,0) ML(6,2,0)  ML(7,10,0)
    BQ(2)
    MR(0,1,1)  MR(1,9,1)  MR(2,17,1) MR(3,25,1) MR(4,33,1) MR(5,41,1) ML(6,3,1)  ML(7,11,1)
    BQ(3)
    MR(0,2,2)  MR(1,10,2) MR(2,18,2) MR(3,26,2) MR(4,34,2) MR(5,42,2) ML(6,4,2)  ML(7,12,2)
    BQ(4)
    MR(0,3,3)  MR(1,11,3) MR(2,19,3) MR(3,27,3) MR(4,35,3) MR(5,43,3) ML(6,5,3)  ML(7,13,3)
    BQ(5)
    MR(0,4,4)  MR(1,12,4) MR(2,20,4) MR(3,28,4) MR(4,36,4) MR(5,44,4) ML(6,6,4)  ML(7,14,4)
    BQ(6)
    MR(0,5,5)  MR(1,13,5) MR(2,21,5) MR(3,29,5) MR(4,37,5) MR(5,45,5) ML(6,7,5)  ML(7,15,5)
    BQ(7)
    MR(0,6,6)  MR(1,14,6) MR(2,22,6) MR(3,30,6) MR(4,38,6) ML(5,0,6)  ML(6,8,6)  ML(7,16,6)
    MR(0,7,7)  MR(1,15,7) MR(2,23,7) MR(3,31,7) MR(4,39,7) ML(5,1,7)  ML(6,9,7)  ML(7,17,7)

    if ((L & 15) == 0) {
      ZST(0) ZST(1) ZST(2) ZST(3) ZST(4) ZST(5) ZST(6) ZST(7)
    }
    __syncthreads();
    if (tid < 256) {
      float zi = z_lds[tid], zf = z_lds[256 + tid];
      float zg = z_lds[512 + tid], zo = z_lds[768 + tid];
      float ig = 1.f / (1.f + __expf(-zi));
      float fg = 1.f / (1.f + __expf(-zf));
      float gg = 1.f - 2.f / (1.f + __expf(2.f * zg));
      float og = 1.f / (1.f + __expf(-zo));
      c_st = fg * c_st + ig * gg;
      float hv = og * (1.f - 2.f / (1.f + __expf(2.f * c_st)));
      encb[t * 256 + tid] = hv;
      h_lds[tid] = (f16)hv;
    }
    __syncthreads();
  }
}

extern "C" void kernel_launch(void* const* d_in, const int* in_sizes, int n_in,
                              void* d_out, int out_size, void* d_ws, size_t ws_size,
                              hipStream_t stream) {
  const float* X = (const float*)d_in[0];
  const float* Wa = (const float*)d_in[1];
  const float* Wl = (const float*)d_in[3];
  const float* Ul = (const float*)d_in[4];
  const float* bl = (const float*)d_in[5];
  float* out = (float*)d_out;
  uint8_t* ws = (uint8_t*)d_ws;

  float* alpha = (float*)ws;                          // 131072 B
  uint32_t* u_mfma = (uint32_t*)(ws + 131072);        // 524288 B
  f16* wt = (f16*)(ws + 655360);                      // 524288 B
  f16* xw = (f16*)(ws + 1179648);                     // 66846720 B (~68 MB total)

  k0_pack<<<1024, 256, 0, stream>>>(Wl, Ul, u_mfma, wt);
  k1_alpha<<<128, 256, 0, stream>>>(X, Wa, alpha);
  k2_xtilde<<<8160, 256, 0, stream>>>((const float4*)X, alpha, (float4*)out);
  dim3 g3(255, 8);
  k3_gemm<<<g3, 256, 0, stream>>>(out, wt, bl, xw);
  k4_recur<<<128, 512, 0, stream>>>(X, (const uint4*)u_mfma, xw,
                                    out + 8355840);
}